// Round 8
// baseline (431.252 us; speedup 1.0000x reference)
//
#include <hip/hip_runtime.h>
#include <hip/hip_bf16.h>
#include <stdint.h>

#define DM   2048
#define SEQ  2048
#define NB   2
#define NH   16
#define DK   128
#define MTOT (NB * SEQ) // 4096
#define NT   (SEQ / 64) // 32 k-tiles

typedef __bf16 bf16;
typedef _Float16 f16;
typedef __bf16 bf16x8 __attribute__((ext_vector_type(8)));
typedef __bf16 bf16x4v __attribute__((ext_vector_type(4)));
typedef _Float16 f16x4 __attribute__((ext_vector_type(4)));
typedef float f32x4 __attribute__((ext_vector_type(4)));
typedef float f32x16 __attribute__((ext_vector_type(16)));

__device__ __forceinline__ void gload_lds16(const void* g, void* l) {
  __builtin_amdgcn_global_load_lds((__attribute__((address_space(1))) void*)(g),
                                   (__attribute__((address_space(3))) void*)(l),
                                   16, 0, 0);
}

__device__ __forceinline__ f32x4 mfma16(bf16x8 a, bf16x8 b, f32x4 c) {
  return __builtin_amdgcn_mfma_f32_16x16x32_bf16(a, b, c, 0, 0, 0);
}
__device__ __forceinline__ f32x16 mfma32(bf16x8 a, bf16x8 b, f32x16 c) {
  return __builtin_amdgcn_mfma_f32_32x32x16_bf16(a, b, c, 0, 0, 0);
}
__device__ __forceinline__ uint32_t cvtpk(float lo, float hi) {
  uint32_t r;
  asm("v_cvt_pk_bf16_f32 %0, %1, %2" : "=v"(r) : "v"(lo), "v"(hi));
  return r;
}
__device__ __forceinline__ float exp2_fast(float x) {
  float r;
  asm("v_exp_f32 %0, %1" : "=v"(r) : "v"(x));
  return r;
}

// ---------------- fp32 -> bf16 cast ----------------
__global__ void cast_kernel(const float* __restrict__ in, bf16* __restrict__ out, int n4) {
  int i = blockIdx.x * blockDim.x + threadIdx.x;
  if (i < n4) {
    float4 v = reinterpret_cast<const float4*>(in)[i];
    bf16x4v o;
    o[0] = (bf16)v.x; o[1] = (bf16)v.y; o[2] = (bf16)v.z; o[3] = (bf16)v.w;
    *reinterpret_cast<bf16x4v*>(out + (size_t)i * 4) = o;
  }
}

// ---------------- fp32 -> fp16 cast (bias mask) ----------------
__global__ void cast_half_kernel(const float* __restrict__ in, f16* __restrict__ out, int n4) {
  int i = blockIdx.x * blockDim.x + threadIdx.x;
  if (i < n4) {
    float4 v = reinterpret_cast<const float4*>(in)[i];
    f16x4 o;
    o[0] = (f16)v.x; o[1] = (f16)v.y; o[2] = (f16)v.z; o[3] = (f16)v.w;
    *reinterpret_cast<f16x4*>(out + (size_t)i * 4) = o;
  }
}

// ---------------- GEMM: C[M,N] = A[M,K] * W[N,K]^T + bias ----------------
template <int MODE>
__global__ __launch_bounds__(256, 2) void gemm_bt(
    const bf16* __restrict__ A, const bf16* __restrict__ W,
    const float* __restrict__ bias, void* __restrict__ out) {
  __shared__ bf16 lA[128 * 64];
  __shared__ bf16 lB[128 * 64];

  const int tid = threadIdx.x;
  const int lane = tid & 63;
  const int wid = tid >> 6;
  const int wr = wid >> 1, wc = wid & 1;
  const int row0 = blockIdx.y * 128;
  const int col0 = blockIdx.x * 128;

  const int srow = lane >> 3;
  const int scol = ((lane & 7) ^ srow) * 8;

  const int fr = lane & 15;
  const int fg = lane >> 4;

  f32x4 acc[4][4];
#pragma unroll
  for (int m = 0; m < 4; ++m)
#pragma unroll
    for (int n = 0; n < 4; ++n) { f32x4 z = {0.f, 0.f, 0.f, 0.f}; acc[m][n] = z; }

  for (int kt = 0; kt < DM / 64; ++kt) {
    const int k0 = kt * 64;
    __syncthreads();
#pragma unroll
    for (int i = 0; i < 4; ++i) {
      const int chunk = wid * 4 + i;
      const int r = chunk * 8 + srow;
      gload_lds16(A + (size_t)(row0 + r) * DM + k0 + scol, lA + chunk * 512);
      gload_lds16(W + (size_t)(col0 + r) * DM + k0 + scol, lB + chunk * 512);
    }
    __syncthreads();
#pragma unroll
    for (int kk = 0; kk < 2; ++kk) {
      bf16x8 af[4], bw[4];
#pragma unroll
      for (int m = 0; m < 4; ++m) {
        const int r = wr * 64 + m * 16 + fr;
        const int cb = (kk * 64 + fg * 16) ^ ((r & 7) << 4);
        af[m] = *(const bf16x8*)((const char*)lA + r * 128 + cb);
      }
#pragma unroll
      for (int n = 0; n < 4; ++n) {
        const int r = wc * 64 + n * 16 + fr;
        const int cb = (kk * 64 + fg * 16) ^ ((r & 7) << 4);
        bw[n] = *(const bf16x8*)((const char*)lB + r * 128 + cb);
      }
#pragma unroll
      for (int m = 0; m < 4; ++m)
#pragma unroll
        for (int n = 0; n < 4; ++n) acc[m][n] = mfma16(af[m], bw[n], acc[m][n]);
    }
  }

#pragma unroll
  for (int m = 0; m < 4; ++m) {
#pragma unroll
    for (int n = 0; n < 4; ++n) {
      const int col = col0 + wc * 64 + n * 16 + fr;
      const float bs = bias[col];
      const int rbase = row0 + wr * 64 + m * 16 + fg * 4;
      if (MODE == 0) {
        bf16* o = (bf16*)out;
        const int h = col >> 7, d = col & 127;
#pragma unroll
        for (int r = 0; r < 4; ++r) {
          const int row = rbase + r;
          const int b = row >> 11, s = row & 2047;
          o[(((size_t)(b * NH + h) * SEQ + s) << 7) + d] = (bf16)(acc[m][n][r] + bs);
        }
      } else if (MODE == 1) {
        bf16* o = (bf16*)out;
        const int h = col >> 7, d = col & 127;
        const int b = rbase >> 11, s = rbase & 2047;
        bf16x4v pk;
#pragma unroll
        for (int r = 0; r < 4; ++r) pk[r] = (bf16)(acc[m][n][r] + bs);
        *reinterpret_cast<bf16x4v*>(o + ((size_t)((b * NH + h) * DK + d) * SEQ + s)) = pk;
      } else {
        float* o = (float*)out;
#pragma unroll
        for (int r = 0; r < 4; ++r) {
          const int row = rbase + r;
          o[(size_t)row * DM + col] = acc[m][n][r] + bs;
        }
      }
    }
  }
}

// ---------------- flash attention: cross-tile pipelined swapped-QK^T ----------------
// body(t): wait(counted) -> barrier -> stage K(t+2),V(t+1) -> QK(t+1)->pNext
//          -> softmax(t) on pCur (hidden under QK exec) -> mask(t+1) -> PV(t) -> sum.
// Two named score/mask register sets (A/B), loop unrolled x2. One barrier/tile.
__global__ __launch_bounds__(256, 2) void attn_kernel(
    const bf16* __restrict__ Q,   // [B,H,S,DK]
    const bf16* __restrict__ K,   // [B,H,S,DK]
    const bf16* __restrict__ Vt,  // [B,H,DK,S]
    const f16* __restrict__ maskh,    // [B,S,S] fp16
    const float* __restrict__ hscale, // [NH]
    bf16* __restrict__ O) {           // [B,S,H,DK]
  __shared__ bf16 Kl[2][64 * 128];  // K(t) lives in Kl[t&1]; 256B rows, slot = col16 ^ (row&15)
  __shared__ bf16 Vl[2][64 * 128];  // V(t) in Vl[t&1]; pair-rows (vp=d>>1), slot = gl ^ (vp&15)

  const int tid = threadIdx.x;
  const int lane = tid & 63;
  const int wv = tid >> 6;
  const int l31 = lane & 31;
  const int hi = lane >> 5;
  const int ksw16 = (l31 & 15) << 4;
  const int vpbase = l31 >> 1;
  const int pvg = (l31 & 1) * 8 + hi;

  // block remap: heads of one (b,qtile) share an XCD
  const int bid = blockIdx.x;
  const int xcd = bid & 7;
  const int slot_ = bid >> 3;
  const int g = xcd + ((slot_ >> 4) << 3);
  const int h = slot_ & 15;
  const int qt = g & 15;
  const int b = g >> 4;
  const int q0 = qt * 128;

  const float ksc2 = 0.08838834764831845f * 1.44269504f;
  const float hs2 = hscale[h] * 1.44269504f;

  const size_t bh = (size_t)(b * NH + h);
  const bf16* Qb = Q + bh * SEQ * DK;
  const bf16* Kb = K + bh * SEQ * DK;
  const bf16* Vb = Vt + bh * (size_t)DK * SEQ;
  const f16*  Mrow = maskh + (size_t)b * SEQ * SEQ + (size_t)(q0 + wv * 32 + l31) * SEQ;

  bf16x8 qreg[8];
  {
    const bf16* qrow = Qb + (size_t)(q0 + wv * 32 + l31) * DK + hi * 8;
#pragma unroll
    for (int s = 0; s < 8; ++s) qreg[s] = *(const bf16x8*)(qrow + s * 16);
  }

  f32x16 acco[4];
#pragma unroll
  for (int nd = 0; nd < 4; ++nd) acco[nd] = (f32x16)(0.0f);
  float m_ = -3.0e38f, l_ = 0.f;

  const int st_sub = lane >> 4;
  const int st_gl0 = lane & 15;

#define STAGE_K(KT, BUF)                                                        \
  {                                                                             \
    _Pragma("unroll")                                                           \
    for (int i = 0; i < 4; ++i) {                                               \
      const int chunk = wv * 4 + i;                                             \
      const int r = chunk * 4 + st_sub;                                         \
      const int gl = st_gl0 ^ (r & 15);                                         \
      gload_lds16(Kb + (size_t)((KT) * 64 + r) * DK + gl * 8, Kl[BUF] + chunk * 512); \
    }                                                                           \
  }
#define STAGE_V(VTT, BUF)                                                       \
  {                                                                             \
    _Pragma("unroll")                                                           \
    for (int i = 0; i < 4; ++i) {                                               \
      const int chunk = wv * 4 + i;                                             \
      const int vp = chunk * 4 + st_sub;                                        \
      const int gl = st_gl0 ^ (vp & 15);                                        \
      const int d = 2 * vp + (gl >> 3);                                         \
      gload_lds16(Vb + (size_t)d * SEQ + (VTT) * 64 + (gl & 7) * 8, Vl[BUF] + chunk * 512); \
    }                                                                           \
  }
#define LOAD_MASK(T, MDST)                                                      \
  {                                                                             \
    _Pragma("unroll")                                                           \
    for (int st = 0; st < 2; ++st)                                              \
      _Pragma("unroll")                                                         \
      for (int c = 0; c < 4; ++c)                                               \
        MDST[st * 4 + c] = *(const f16x4*)(Mrow + (T) * 64 + st * 32 + c * 8 + hi * 4); \
  }
#define QK_TILE(T, P0, P1)                                                      \
  {                                                                             \
    P0 = (f32x16)(0.0f); P1 = (f32x16)(0.0f);                                   \
    const bf16* Kc_ = Kl[(T) & 1];                                              \
    __builtin_amdgcn_s_setprio(1);                                              \
    _Pragma("unroll")                                                           \
    for (int s = 0; s < 8; ++s) {                                               \
      const int byteoff = (s * 32 + hi * 16) ^ ksw16;                           \
      bf16x8 k0_ = *(const bf16x8*)((const char*)Kc_ + (size_t)l31 * 256 + byteoff);       \
      bf16x8 k1_ = *(const bf16x8*)((const char*)Kc_ + (size_t)(32 + l31) * 256 + byteoff); \
      P0 = mfma32(k0_, qreg[s], P0);                                            \
      P1 = mfma32(k1_, qreg[s], P1);                                            \
    }                                                                           \
    __builtin_amdgcn_s_setprio(0);                                              \
  }

  // ---- prologue: mask(0); stage K0,V0,K1; wait own K0/V0; barrier; QK(0)
  f16x4 mkA[8], mkB[8];
  f32x16 pA0, pA1, pB0, pB1;

  LOAD_MASK(0, mkA);
  STAGE_K(0, 0);
  STAGE_V(0, 0);
  STAGE_K(1, 1);
  asm volatile("s_waitcnt vmcnt(4)" ::: "memory");   // K0,V0 landed (K1 young)
  __builtin_amdgcn_sched_barrier(0);
  __builtin_amdgcn_s_barrier();
  __builtin_amdgcn_sched_barrier(0);
  QK_TILE(0, pA0, pA1);

#define BODY(T, VMCNT_ASM, PC0, PC1, MC, PN0, PN1, MN)                          \
  {                                                                             \
    const int t_ = (T);                                                         \
    asm volatile(VMCNT_ASM ::: "memory");                                       \
    __builtin_amdgcn_sched_barrier(0);                                          \
    __builtin_amdgcn_s_barrier();                                               \
    __builtin_amdgcn_sched_barrier(0);                                          \
    if (t_ + 2 < NT) STAGE_K(t_ + 2, t_ & 1);                                   \
    if (t_ + 1 < NT) STAGE_V(t_ + 1, (t_ + 1) & 1);                             \
    if (t_ + 1 < NT) QK_TILE(t_ + 1, PN0, PN1);                                 \
    /* softmax(t) on PC/MC */                                                   \
    float lg[32];                                                               \
    _Pragma("unroll")                                                           \
    for (int r = 0; r < 16; ++r) {                                              \
      lg[r]      = PC0[r] * ksc2 + (float)MC[r >> 2][r & 3] * hs2;              \
      lg[16 + r] = PC1[r] * ksc2 + (float)MC[4 + (r >> 2)][r & 3] * hs2;        \
    }                                                                           \
    float tm[16];                                                               \
    _Pragma("unroll")                                                           \
    for (int i = 0; i < 16; ++i) tm[i] = fmaxf(lg[i], lg[i + 16]);              \
    _Pragma("unroll")                                                           \
    for (int i = 0; i < 8; ++i) tm[i] = fmaxf(tm[i], tm[i + 8]);                \
    _Pragma("unroll")                                                           \
    for (int i = 0; i < 4; ++i) tm[i] = fmaxf(tm[i], tm[i + 4]);                \
    float mx = fmaxf(fmaxf(tm[0], tm[1]), fmaxf(tm[2], tm[3]));                 \
    mx = fmaxf(mx, __shfl_xor(mx, 32));                                         \
    if (__any(mx - m_ > 11.5416f)) {                                            \
      const float mnew = fmaxf(m_, mx);                                         \
      const float sc = exp2_fast(m_ - mnew);                                    \
      m_ = mnew;                                                                \
      l_ *= sc;                                                                 \
      _Pragma("unroll")                                                         \
      for (int r = 0; r < 16; ++r) {                                            \
        const float scr = __shfl(sc, (r & 3) + 8 * (r >> 2) + 4 * hi);          \
        _Pragma("unroll")                                                       \
        for (int nd = 0; nd < 4; ++nd) acco[nd][r] *= scr;                      \
      }                                                                         \
    }                                                                           \
    _Pragma("unroll")                                                           \
    for (int i = 0; i < 32; ++i) lg[i] = exp2_fast(lg[i] - m_);                 \
    bf16x8 pa[4];                                                               \
    _Pragma("unroll")                                                           \
    for (int ks = 0; ks < 4; ++ks) {                                            \
      const int bo = (ks & 1) * 8 + ((ks >> 1) << 4);                           \
      const uint32_t w0 = cvtpk(lg[bo + 0], lg[bo + 1]);                        \
      const uint32_t w1 = cvtpk(lg[bo + 2], lg[bo + 3]);                        \
      const uint32_t w2 = cvtpk(lg[bo + 4], lg[bo + 5]);                        \
      const uint32_t w3 = cvtpk(lg[bo + 6], lg[bo + 7]);                        \
      const uint32_t x0 = __shfl_xor(w0, 32);                                   \
      const uint32_t x1 = __shfl_xor(w1, 32);                                   \
      const uint32_t x2 = __shfl_xor(w2, 32);                                   \
      const uint32_t x3 = __shfl_xor(w3, 32);                                   \
      union { uint32_t u[4]; bf16x8 v; } pk_;                                   \
      pk_.u[0] = hi ? x2 : w0;                                                  \
      pk_.u[1] = hi ? x3 : w1;                                                  \
      pk_.u[2] = hi ? w2 : x0;                                                  \
      pk_.u[3] = hi ? w3 : x1;                                                  \
      pa[ks] = pk_.v;                                                           \
    }                                                                           \
    if (t_ + 1 < NT) LOAD_MASK(t_ + 1, MN);                                     \
    /* PV(t) */                                                                 \
    {                                                                           \
      const bf16* Vc_ = Vl[t_ & 1];                                             \
      __builtin_amdgcn_s_setprio(1);                                            \
      _Pragma("unroll")                                                         \
      for (int nd = 0; nd < 4; ++nd) {                                          \
        const int vrow = (nd * 16 + vpbase) * 256;                              \
        _Pragma("unroll")                                                       \
        for (int ks = 0; ks < 4; ++ks) {                                        \
          const int slot = (pvg + ks * 2) ^ vpbase;                             \
          bf16x8 vf = *(const bf16x8*)((const char*)Vc_ + vrow + slot * 16);    \
          acco[nd] = mfma32(pa[ks], vf, acco[nd]);                              \
        }                                                                       \
      }                                                                         \
      __builtin_amdgcn_s_setprio(0);                                            \
    }                                                                           \
    /* row sum off critical path */                                             \
    float ts[16];                                                               \
    _Pragma("unroll")                                                           \
    for (int i = 0; i < 16; ++i) ts[i] = lg[i] + lg[i + 16];                    \
    _Pragma("unroll")                                                           \
    for (int i = 0; i < 8; ++i) ts[i] = ts[i] + ts[i + 8];                      \
    _Pragma("unroll")                                                           \
    for (int i = 0; i < 4; ++i) ts[i] = ts[i] + ts[i + 4];                      \
    float es = (ts[0] + ts[1]) + (ts[2] + ts[3]);                               \
    es += __shfl_xor(es, 32);                                                   \
    l_ += es;                                                                   \
  }

  // mask viewed as [8] of f16x4 -> adapt indexing: MC[r>>2][r&3] with MC as f16x4[8]
  // (handled: mkA[st*4+c]; softmax uses MC[r>>2] for st=0 rows, MC[4+(r>>2)] for st=1)

  BODY(0, "s_waitcnt vmcnt(0)", pA0, pA1, mkA, pB0, pB1, mkB);
  BODY(1, "s_waitcnt vmcnt(8)", pB0, pB1, mkB, pA0, pA1, mkA);
  for (int tt = 2; tt < NT; tt += 2) {
    BODY(tt,     "s_waitcnt vmcnt(8)", pA0, pA1, mkA, pB0, pB1, mkB);
    BODY(tt + 1, "s_waitcnt vmcnt(8)", pB0, pB1, mkB, pA0, pA1, mkA);
  }

  // epilogue: normalize and store [B,S,H,DK]
  const float inv = 1.f / l_;
#pragma unroll
  for (int r = 0; r < 16; ++r) {
    const int qloc = (r & 3) + 8 * (r >> 2) + 4 * hi;
    const float ivr = __shfl(inv, qloc);
    const int q_abs = q0 + wv * 32 + qloc;
    bf16* orow = O + (((size_t)(b * SEQ + q_abs) * NH + h) << 7) + l31;
#pragma unroll
    for (int nd = 0; nd < 4; ++nd) orow[nd * 32] = (bf16)(acco[nd][r] * ivr);
  }
#undef BODY
#undef QK_TILE
#undef LOAD_MASK
#undef STAGE_V
#undef STAGE_K
}

extern "C" void kernel_launch(void* const* d_in, const int* in_sizes, int n_in,
                              void* d_out, int out_size, void* d_ws, size_t ws_size,
                              hipStream_t stream) {
  const float* states = (const float*)d_in[0];
  const float* maskp  = (const float*)d_in[1];
  const float* hscale = (const float*)d_in[2];
  const float* qw = (const float*)d_in[3];
  const float* qb = (const float*)d_in[4];
  const float* kw = (const float*)d_in[5];
  const float* kb = (const float*)d_in[6];
  const float* vw = (const float*)d_in[7];
  const float* vb = (const float*)d_in[8];
  const float* ow = (const float*)d_in[9];
  const float* ob = (const float*)d_in[10];

  char* ws = (char*)d_ws;
  const size_t SZ_ACT = (size_t)MTOT * DM * 2;  // 16 MiB
  const size_t SZ_W   = (size_t)DM * DM * 2;    // 8 MiB
  bf16* sb    = (bf16*)(ws);
  bf16* qbuf  = (bf16*)(ws + SZ_ACT);
  bf16* kbuf  = (bf16*)(ws + 2 * SZ_ACT);
  bf16* vtbuf = (bf16*)(ws + 3 * SZ_ACT);
  bf16* wqb   = (bf16*)(ws + 4 * SZ_ACT);
  bf16* wkb   = (bf16*)(ws + 4 * SZ_ACT + SZ_W);
  bf16* wvb   = (bf16*)(ws + 4 * SZ_ACT + 2 * SZ_W);
  bf16* wob   = (bf16*)(ws + 4 * SZ_ACT + 3 * SZ_W);
  f16* maskh  = (f16*)(ws + 4 * SZ_ACT);        // reuses wq/wk region

  const int nAct4 = MTOT * DM / 4;
  const int nW4   = DM * DM / 4;
  const int nM4   = NB * SEQ * SEQ / 4;
  cast_kernel<<<(nAct4 + 255) / 256, 256, 0, stream>>>(states, sb, nAct4);
  cast_kernel<<<(nW4 + 255) / 256, 256, 0, stream>>>(qw, wqb, nW4);
  cast_kernel<<<(nW4 + 255) / 256, 256, 0, stream>>>(kw, wkb, nW4);
  cast_kernel<<<(nW4 + 255) / 256, 256, 0, stream>>>(vw, wvb, nW4);
  cast_kernel<<<(nW4 + 255) / 256, 256, 0, stream>>>(ow, wob, nW4);

  dim3 blk(256);
  dim3 gg(DM / 128, MTOT / 128, 1);
  gemm_bt<0><<<gg, blk, 0, stream>>>(sb, wqb, qb, qbuf);
  gemm_bt<0><<<gg, blk, 0, stream>>>(sb, wkb, kb, kbuf);
  gemm_bt<1><<<gg, blk, 0, stream>>>(sb, wvb, vb, vtbuf);

  cast_half_kernel<<<(nM4 + 255) / 256, 256, 0, stream>>>(maskp, maskh, nM4);

  attn_kernel<<<dim3(NB * NH * (SEQ / 128)), blk, 0, stream>>>(qbuf, kbuf, vtbuf, maskh, hscale, sb);

  gemm_bt<2><<<gg, blk, 0, stream>>>(sb, wob, ob, d_out);
}

// Round 9
// 362.263 us; speedup vs baseline: 1.1904x; 1.1904x over previous
//
#include <hip/hip_runtime.h>
#include <hip/hip_bf16.h>
#include <stdint.h>

#define DM   2048
#define SEQ  2048
#define NB   2
#define NH   16
#define DK   128
#define MTOT (NB * SEQ) // 4096
#define NT   (SEQ / 64) // 32 k-tiles

typedef __bf16 bf16;
typedef _Float16 f16;
typedef __bf16 bf16x8 __attribute__((ext_vector_type(8)));
typedef __bf16 bf16x4v __attribute__((ext_vector_type(4)));
typedef _Float16 f16x4 __attribute__((ext_vector_type(4)));
typedef float f32x4 __attribute__((ext_vector_type(4)));
typedef float f32x16 __attribute__((ext_vector_type(16)));

__device__ __forceinline__ void gload_lds16(const void* g, void* l) {
  __builtin_amdgcn_global_load_lds((__attribute__((address_space(1))) void*)(g),
                                   (__attribute__((address_space(3))) void*)(l),
                                   16, 0, 0);
}

__device__ __forceinline__ f32x4 mfma16(bf16x8 a, bf16x8 b, f32x4 c) {
  return __builtin_amdgcn_mfma_f32_16x16x32_bf16(a, b, c, 0, 0, 0);
}
__device__ __forceinline__ f32x16 mfma32(bf16x8 a, bf16x8 b, f32x16 c) {
  return __builtin_amdgcn_mfma_f32_32x32x16_bf16(a, b, c, 0, 0, 0);
}
__device__ __forceinline__ uint32_t cvtpk(float lo, float hi) {
  uint32_t r;
  asm("v_cvt_pk_bf16_f32 %0, %1, %2" : "=v"(r) : "v"(lo), "v"(hi));
  return r;
}
__device__ __forceinline__ float exp2_fast(float x) {
  float r;
  asm("v_exp_f32 %0, %1" : "=v"(r) : "v"(x));
  return r;
}

// ---------------- fp32 -> bf16 cast ----------------
__global__ void cast_kernel(const float* __restrict__ in, bf16* __restrict__ out, int n4) {
  int i = blockIdx.x * blockDim.x + threadIdx.x;
  if (i < n4) {
    float4 v = reinterpret_cast<const float4*>(in)[i];
    bf16x4v o;
    o[0] = (bf16)v.x; o[1] = (bf16)v.y; o[2] = (bf16)v.z; o[3] = (bf16)v.w;
    *reinterpret_cast<bf16x4v*>(out + (size_t)i * 4) = o;
  }
}

// ---------------- fp32 -> fp16 cast (bias mask) ----------------
__global__ void cast_half_kernel(const float* __restrict__ in, f16* __restrict__ out, int n4) {
  int i = blockIdx.x * blockDim.x + threadIdx.x;
  if (i < n4) {
    float4 v = reinterpret_cast<const float4*>(in)[i];
    f16x4 o;
    o[0] = (f16)v.x; o[1] = (f16)v.y; o[2] = (f16)v.z; o[3] = (f16)v.w;
    *reinterpret_cast<f16x4*>(out + (size_t)i * 4) = o;
  }
}

// ---------------- GEMM 256x128, 8 waves, counted-vmcnt pipeline ----------------
// C[M,N] = A[M,K] * W[N,K]^T + bias.  MODE 0: bf16 [B,H,S,DK]; 1: bf16 [B,H,DK,S]; 2: f32 [M,N].
// Wave (wr=wid>>1 in [0,4), wc=wid&1 in [0,2)) owns a 64x64 output tile; acc[4][4] f32x4.
// LDS: A 256x64 + B 128x64, double-buffered (96 KB). Stage(t+1) issued BEFORE vmcnt(6):
// stage(t) drains while t+1's loads stay in flight (T4). 32 MFMA per barrier pair.
template <int MODE>
__global__ __launch_bounds__(512, 2) void gemm_bt(
    const bf16* __restrict__ A, const bf16* __restrict__ W,
    const float* __restrict__ bias, void* __restrict__ out) {
  __shared__ bf16 lA[2][256 * 64];  // 2 x 32 KB
  __shared__ bf16 lB[2][128 * 64];  // 2 x 16 KB

  const int tid = threadIdx.x;
  const int lane = tid & 63;
  const int wid = tid >> 6;          // 0..7
  const int wr = wid >> 1, wc = wid & 1;
  const int row0 = blockIdx.y * 256;
  const int col0 = blockIdx.x * 128;

  const int srow = lane >> 3;                 // row within 8-row chunk
  const int sgl  = (lane & 7) ^ srow;         // pre-swizzled source granule

  const int fr = lane & 15;
  const int fg = lane >> 4;

  f32x4 acc[4][4];
#pragma unroll
  for (int m = 0; m < 4; ++m)
#pragma unroll
    for (int n = 0; n < 4; ++n) { f32x4 z = {0.f, 0.f, 0.f, 0.f}; acc[m][n] = z; }

#define G_STAGE(KT, BUF)                                                          \
  {                                                                               \
    const int k0_ = (KT) * 64;                                                    \
    _Pragma("unroll")                                                             \
    for (int i = 0; i < 4; ++i) {  /* A: 32 chunks of 8 rows */                   \
      const int chunk = i * 8 + wid;                                              \
      const int r = chunk * 8 + srow;                                             \
      gload_lds16(A + (size_t)(row0 + r) * DM + k0_ + sgl * 8,                    \
                  lA[BUF] + chunk * 512);                                         \
    }                                                                             \
    _Pragma("unroll")                                                             \
    for (int i = 0; i < 2; ++i) {  /* B: 16 chunks of 8 rows */                   \
      const int chunk = i * 8 + wid;                                              \
      const int r = chunk * 8 + srow;                                             \
      gload_lds16(W + (size_t)(col0 + r) * DM + k0_ + sgl * 8,                    \
                  lB[BUF] + chunk * 512);                                         \
    }                                                                             \
  }

  // prologue: stage tile 0
  G_STAGE(0, 0);

  for (int t = 0; t < DM / 64; ++t) {
    const int c = t & 1;
    if (t + 1 < DM / 64) {
      G_STAGE(t + 1, c ^ 1);
      asm volatile("s_waitcnt vmcnt(6)" ::: "memory");  // stage(t) done; t+1 in flight
    } else {
      asm volatile("s_waitcnt vmcnt(0)" ::: "memory");
    }
    __builtin_amdgcn_sched_barrier(0);
    __builtin_amdgcn_s_barrier();
    __builtin_amdgcn_sched_barrier(0);

    const bf16* Ac = lA[c];
    const bf16* Bc = lB[c];
    // B fragments for both kk (held in regs across the m-loop)
    bf16x8 bfr[2][4];
#pragma unroll
    for (int kk = 0; kk < 2; ++kk)
#pragma unroll
      for (int n = 0; n < 4; ++n) {
        const int r = wc * 64 + n * 16 + fr;
        const int cb = (kk * 64 + fg * 16) ^ ((r & 7) << 4);
        bfr[kk][n] = *(const bf16x8*)((const char*)Bc + r * 128 + cb);
      }
#pragma unroll
    for (int m = 0; m < 4; ++m) {
      const int r = wr * 64 + m * 16 + fr;
      const int cb0 = (fg * 16) ^ ((r & 7) << 4);
      const int cb1 = (64 + fg * 16) ^ ((r & 7) << 4);
      bf16x8 af0 = *(const bf16x8*)((const char*)Ac + r * 128 + cb0);
      bf16x8 af1 = *(const bf16x8*)((const char*)Ac + r * 128 + cb1);
      __builtin_amdgcn_s_setprio(1);
#pragma unroll
      for (int n = 0; n < 4; ++n) acc[m][n] = mfma16(af0, bfr[0][n], acc[m][n]);
#pragma unroll
      for (int n = 0; n < 4; ++n) acc[m][n] = mfma16(af1, bfr[1][n], acc[m][n]);
      __builtin_amdgcn_s_setprio(0);
    }

    // all waves done reading buf c before it is restaged next iteration
    asm volatile("s_waitcnt lgkmcnt(0)" ::: "memory");
    __builtin_amdgcn_sched_barrier(0);
    __builtin_amdgcn_s_barrier();
  }
#undef G_STAGE

#pragma unroll
  for (int m = 0; m < 4; ++m) {
#pragma unroll
    for (int n = 0; n < 4; ++n) {
      const int col = col0 + wc * 64 + n * 16 + fr;
      const float bs = bias[col];
      const int rbase = row0 + wr * 64 + m * 16 + fg * 4;
      if (MODE == 0) {
        bf16* o = (bf16*)out;
        const int h = col >> 7, d = col & 127;
#pragma unroll
        for (int r = 0; r < 4; ++r) {
          const int row = rbase + r;
          const int b = row >> 11, s = row & 2047;
          o[(((size_t)(b * NH + h) * SEQ + s) << 7) + d] = (bf16)(acc[m][n][r] + bs);
        }
      } else if (MODE == 1) {
        bf16* o = (bf16*)out;
        const int h = col >> 7, d = col & 127;
        const int b = rbase >> 11, s = rbase & 2047;
        bf16x4v pk;
#pragma unroll
        for (int r = 0; r < 4; ++r) pk[r] = (bf16)(acc[m][n][r] + bs);
        *reinterpret_cast<bf16x4v*>(o + ((size_t)((b * NH + h) * DK + d) * SEQ + s)) = pk;
      } else {
        float* o = (float*)out;
#pragma unroll
        for (int r = 0; r < 4; ++r) {
          const int row = rbase + r;
          o[(size_t)row * DM + col] = acc[m][n][r] + bs;
        }
      }
    }
  }
}

// ---------------- flash attention: swapped QK^T, in-register softmax (R7, verified) ----------------
__global__ __launch_bounds__(256, 2) void attn_kernel(
    const bf16* __restrict__ Q,   // [B,H,S,DK]
    const bf16* __restrict__ K,   // [B,H,S,DK]
    const bf16* __restrict__ Vt,  // [B,H,DK,S]
    const f16* __restrict__ maskh,    // [B,S,S] fp16
    const float* __restrict__ hscale, // [NH]
    bf16* __restrict__ O) {           // [B,S,H,DK]
  __shared__ bf16 Kl[2][64 * 128];  // 256B rows, granule slot = col16 ^ (row&15)
  __shared__ bf16 Vl[2][64 * 128];  // pair-rows (vp=d>>1) of 256B, slot = gl ^ (vp&15)

  const int tid = threadIdx.x;
  const int lane = tid & 63;
  const int wv = tid >> 6;
  const int l31 = lane & 31;
  const int hi = lane >> 5;
  const int ksw16 = (l31 & 15) << 4;
  const int vpbase = l31 >> 1;
  const int pvg = (l31 & 1) * 8 + hi;

  const int bid = blockIdx.x;
  const int xcd = bid & 7;
  const int slot_ = bid >> 3;
  const int g = xcd + ((slot_ >> 4) << 3);
  const int h = slot_ & 15;
  const int qt = g & 15;
  const int b = g >> 4;
  const int q0 = qt * 128;

  const float ksc2 = 0.08838834764831845f * 1.44269504f;
  const float hs2 = hscale[h] * 1.44269504f;

  const size_t bh = (size_t)(b * NH + h);
  const bf16* Qb = Q + bh * SEQ * DK;
  const bf16* Kb = K + bh * SEQ * DK;
  const bf16* Vb = Vt + bh * (size_t)DK * SEQ;
  const f16*  Mrow = maskh + (size_t)b * SEQ * SEQ + (size_t)(q0 + wv * 32 + l31) * SEQ;

  bf16x8 qreg[8];
  {
    const bf16* qrow = Qb + (size_t)(q0 + wv * 32 + l31) * DK + hi * 8;
#pragma unroll
    for (int s = 0; s < 8; ++s) qreg[s] = *(const bf16x8*)(qrow + s * 16);
  }

  f32x16 acco[4];
#pragma unroll
  for (int nd = 0; nd < 4; ++nd) acco[nd] = (f32x16)(0.0f);
  float m_ = -3.0e38f, l_ = 0.f;

  const int st_sub = lane >> 4;
  const int st_gl0 = lane & 15;

  // ---- prologue: stage tile 0 (K and V)
#pragma unroll
  for (int i = 0; i < 4; ++i) {
    const int chunk = wv * 4 + i;
    {
      const int r = chunk * 4 + st_sub;
      const int gl = st_gl0 ^ (r & 15);
      gload_lds16(Kb + (size_t)r * DK + gl * 8, Kl[0] + chunk * 512);
    }
    {
      const int vp = chunk * 4 + st_sub;
      const int gl = st_gl0 ^ (vp & 15);
      const int d = 2 * vp + (gl >> 3);
      gload_lds16(Vb + (size_t)d * SEQ + (gl & 7) * 8, Vl[0] + chunk * 512);
    }
  }
  __syncthreads();

  for (int t = 0; t < NT; ++t) {
    const int kb0 = t * 64;
    const int cur = t & 1, nxt = cur ^ 1;
    const bf16* Kc = Kl[cur];
    const bf16* Vc = Vl[cur];

    // 1. mask register loads for this tile
    f16x4 mk[2][4];
#pragma unroll
    for (int st = 0; st < 2; ++st)
#pragma unroll
      for (int c = 0; c < 4; ++c)
        mk[st][c] = *(const f16x4*)(Mrow + kb0 + st * 32 + c * 8 + hi * 4);

    // 2. stage tile t+1 into the other buffers
    if (t + 1 < NT) {
#pragma unroll
      for (int i = 0; i < 4; ++i) {
        const int chunk = wv * 4 + i;
        {
          const int r = chunk * 4 + st_sub;
          const int gl = st_gl0 ^ (r & 15);
          gload_lds16(Kb + (size_t)(kb0 + 64 + r) * DK + gl * 8, Kl[nxt] + chunk * 512);
        }
        {
          const int vp = chunk * 4 + st_sub;
          const int gl = st_gl0 ^ (vp & 15);
          const int d = 2 * vp + (gl >> 3);
          gload_lds16(Vb + (size_t)d * SEQ + kb0 + 64 + (gl & 7) * 8, Vl[nxt] + chunk * 512);
        }
      }
    }

    // 3. QK^T
    f32x16 p[2];
#pragma unroll
    for (int st = 0; st < 2; ++st) p[st] = (f32x16)(0.0f);
    __builtin_amdgcn_s_setprio(1);
#pragma unroll
    for (int s = 0; s < 8; ++s) {
      const int byteoff = (s * 32 + hi * 16) ^ ksw16;
      bf16x8 k0 = *(const bf16x8*)((const char*)Kc + (size_t)l31 * 256 + byteoff);
      bf16x8 k1 = *(const bf16x8*)((const char*)Kc + (size_t)(32 + l31) * 256 + byteoff);
      p[0] = mfma32(k0, qreg[s], p[0]);
      p[1] = mfma32(k1, qreg[s], p[1]);
    }
    __builtin_amdgcn_s_setprio(0);

    // 4. logits in log2 domain
    float lg[32];
#pragma unroll
    for (int st = 0; st < 2; ++st)
#pragma unroll
      for (int r = 0; r < 16; ++r)
        lg[st * 16 + r] = p[st][r] * ksc2 + (float)mk[st][r >> 2][r & 3] * hs2;

    float tm[16];
#pragma unroll
    for (int i = 0; i < 16; ++i) tm[i] = fmaxf(lg[i], lg[i + 16]);
#pragma unroll
    for (int i = 0; i < 8; ++i) tm[i] = fmaxf(tm[i], tm[i + 8]);
#pragma unroll
    for (int i = 0; i < 4; ++i) tm[i] = fmaxf(tm[i], tm[i + 4]);
    float mx = fmaxf(fmaxf(tm[0], tm[1]), fmaxf(tm[2], tm[3]));
    mx = fmaxf(mx, __shfl_xor(mx, 32));

    if (__any(mx - m_ > 11.5416f)) {
      const float mnew = fmaxf(m_, mx);
      const float sc = exp2_fast(m_ - mnew);
      m_ = mnew;
      l_ *= sc;
#pragma unroll
      for (int r = 0; r < 16; ++r) {
        const float scr = __shfl(sc, (r & 3) + 8 * (r >> 2) + 4 * hi);
#pragma unroll
        for (int nd = 0; nd < 4; ++nd) acco[nd][r] *= scr;
      }
    }

#pragma unroll
    for (int i = 0; i < 32; ++i) lg[i] = exp2_fast(lg[i] - m_);
    float ts[16];
#pragma unroll
    for (int i = 0; i < 16; ++i) ts[i] = lg[i] + lg[i + 16];
#pragma unroll
    for (int i = 0; i < 8; ++i) ts[i] = ts[i] + ts[i + 8];
#pragma unroll
    for (int i = 0; i < 4; ++i) ts[i] = ts[i] + ts[i + 4];
    float es = (ts[0] + ts[1]) + (ts[2] + ts[3]);
    es += __shfl_xor(es, 32);
    l_ += es;

    // 5. pack P -> PV A-frags
    bf16x8 pa[4];
#pragma unroll
    for (int ks = 0; ks < 4; ++ks) {
      const int bo = (ks & 1) * 8 + ((ks >> 1) << 4);
      const uint32_t w0 = cvtpk(lg[bo + 0], lg[bo + 1]);
      const uint32_t w1 = cvtpk(lg[bo + 2], lg[bo + 3]);
      const uint32_t w2 = cvtpk(lg[bo + 4], lg[bo + 5]);
      const uint32_t w3 = cvtpk(lg[bo + 6], lg[bo + 7]);
      const uint32_t x0 = __shfl_xor(w0, 32);
      const uint32_t x1 = __shfl_xor(w1, 32);
      const uint32_t x2 = __shfl_xor(w2, 32);
      const uint32_t x3 = __shfl_xor(w3, 32);
      union { uint32_t u[4]; bf16x8 v; } pk;
      pk.u[0] = hi ? x2 : w0;
      pk.u[1] = hi ? x3 : w1;
      pk.u[2] = hi ? w2 : x0;
      pk.u[3] = hi ? w3 : x1;
      pa[ks] = pk.v;
    }

    // 6. PV
    __builtin_amdgcn_s_setprio(1);
#pragma unroll
    for (int nd = 0; nd < 4; ++nd) {
      const int vrow = (nd * 16 + vpbase) * 256;
#pragma unroll
      for (int ks = 0; ks < 4; ++ks) {
        const int slot = (pvg + ks * 2) ^ vpbase;
        bf16x8 vf = *(const bf16x8*)((const char*)Vc + vrow + slot * 16);
        acco[nd] = mfma32(pa[ks], vf, acco[nd]);
      }
    }
    __builtin_amdgcn_s_setprio(0);

    asm volatile("s_waitcnt vmcnt(0) lgkmcnt(0)" ::: "memory");
    __builtin_amdgcn_sched_barrier(0);
    __builtin_amdgcn_s_barrier();
  }

  const float inv = 1.f / l_;
#pragma unroll
  for (int r = 0; r < 16; ++r) {
    const int qloc = (r & 3) + 8 * (r >> 2) + 4 * hi;
    const float ivr = __shfl(inv, qloc);
    const int q_abs = q0 + wv * 32 + qloc;
    bf16* orow = O + (((size_t)(b * SEQ + q_abs) * NH + h) << 7) + l31;
#pragma unroll
    for (int nd = 0; nd < 4; ++nd) orow[nd * 32] = (bf16)(acco[nd][r] * ivr);
  }
}

extern "C" void kernel_launch(void* const* d_in, const int* in_sizes, int n_in,
                              void* d_out, int out_size, void* d_ws, size_t ws_size,
                              hipStream_t stream) {
  const float* states = (const float*)d_in[0];
  const float* maskp  = (const float*)d_in[1];
  const float* hscale = (const float*)d_in[2];
  const float* qw = (const float*)d_in[3];
  const float* qb = (const float*)d_in[4];
  const float* kw = (const float*)d_in[5];
  const float* kb = (const float*)d_in[6];
  const float* vw = (const float*)d_in[7];
  const float* vb = (const float*)d_in[8];
  const float* ow = (const float*)d_in[9];
  const float* ob = (const float*)d_in[10];

  char* ws = (char*)d_ws;
  const size_t SZ_ACT = (size_t)MTOT * DM * 2;  // 16 MiB
  const size_t SZ_W   = (size_t)DM * DM * 2;    // 8 MiB
  bf16* sb    = (bf16*)(ws);
  bf16* qbuf  = (bf16*)(ws + SZ_ACT);
  bf16* kbuf  = (bf16*)(ws + 2 * SZ_ACT);
  bf16* vtbuf = (bf16*)(ws + 3 * SZ_ACT);
  bf16* wqb   = (bf16*)(ws + 4 * SZ_ACT);
  bf16* wkb   = (bf16*)(ws + 4 * SZ_ACT + SZ_W);
  bf16* wvb   = (bf16*)(ws + 4 * SZ_ACT + 2 * SZ_W);
  bf16* wob   = (bf16*)(ws + 4 * SZ_ACT + 3 * SZ_W);
  f16* maskh  = (f16*)(ws + 4 * SZ_ACT);        // reuses wq/wk region (dead after QKV GEMMs)

  const int nAct4 = MTOT * DM / 4;
  const int nW4   = DM * DM / 4;
  const int nM4   = NB * SEQ * SEQ / 4;
  cast_kernel<<<(nAct4 + 255) / 256, 256, 0, stream>>>(states, sb, nAct4);
  cast_kernel<<<(nW4 + 255) / 256, 256, 0, stream>>>(qw, wqb, nW4);
  cast_kernel<<<(nW4 + 255) / 256, 256, 0, stream>>>(kw, wkb, nW4);
  cast_kernel<<<(nW4 + 255) / 256, 256, 0, stream>>>(vw, wvb, nW4);
  cast_kernel<<<(nW4 + 255) / 256, 256, 0, stream>>>(ow, wob, nW4);

  dim3 blkg(512);
  dim3 gg(DM / 128, MTOT / 256, 1);   // 16 x 16 = 256 blocks
  gemm_bt<0><<<gg, blkg, 0, stream>>>(sb, wqb, qb, qbuf);
  gemm_bt<0><<<gg, blkg, 0, stream>>>(sb, wkb, kb, kbuf);
  gemm_bt<1><<<gg, blkg, 0, stream>>>(sb, wvb, vb, vtbuf);

  cast_half_kernel<<<(nM4 + 255) / 256, 256, 0, stream>>>(maskp, maskh, nM4);

  attn_kernel<<<dim3(NB * NH * (SEQ / 128)), dim3(256), 0, stream>>>(qbuf, kbuf, vtbuf, maskh, hscale, sb);

  gemm_bt<2><<<gg, blkg, 0, stream>>>(sb, wob, ob, d_out);
}

// Round 10
// 283.935 us; speedup vs baseline: 1.5188x; 1.2759x over previous
//
#include <hip/hip_runtime.h>
#include <hip/hip_bf16.h>
#include <stdint.h>

#define DM   2048
#define SEQ  2048
#define NB   2
#define NH   16
#define DK   128
#define MTOT (NB * SEQ) // 4096
#define NT   (SEQ / 64) // 32 k-tiles

typedef __bf16 bf16;
typedef _Float16 f16;
typedef __bf16 bf16x8 __attribute__((ext_vector_type(8)));
typedef __bf16 bf16x4v __attribute__((ext_vector_type(4)));
typedef _Float16 f16x4 __attribute__((ext_vector_type(4)));
typedef float f32x4 __attribute__((ext_vector_type(4)));
typedef float f32x16 __attribute__((ext_vector_type(16)));

__device__ __forceinline__ void gload_lds16(const void* g, void* l) {
  __builtin_amdgcn_global_load_lds((__attribute__((address_space(1))) void*)(g),
                                   (__attribute__((address_space(3))) void*)(l),
                                   16, 0, 0);
}

__device__ __forceinline__ f32x4 mfma16(bf16x8 a, bf16x8 b, f32x4 c) {
  return __builtin_amdgcn_mfma_f32_16x16x32_bf16(a, b, c, 0, 0, 0);
}
__device__ __forceinline__ f32x16 mfma32(bf16x8 a, bf16x8 b, f32x16 c) {
  return __builtin_amdgcn_mfma_f32_32x32x16_bf16(a, b, c, 0, 0, 0);
}
__device__ __forceinline__ uint32_t cvtpk(float lo, float hi) {
  uint32_t r;
  asm("v_cvt_pk_bf16_f32 %0, %1, %2" : "=v"(r) : "v"(lo), "v"(hi));
  return r;
}
__device__ __forceinline__ float exp2_fast(float x) {
  float r;
  asm("v_exp_f32 %0, %1" : "=v"(r) : "v"(x));
  return r;
}

// ---------------- fused fp32 -> bf16 cast: states + 4 weights, one launch ----------------
// segments: [0, nAct4) -> states->sb ; [nAct4, nAct4+4*nW4) -> weights (contiguous out).
// nAct4 = 2^21, nW4 = 2^20; block of 256 threads covers 1024 i4 -> segment is block-uniform.
__global__ void cast_all_kernel(const float* __restrict__ s,
                                const float* __restrict__ w0, const float* __restrict__ w1,
                                const float* __restrict__ w2, const float* __restrict__ w3,
                                bf16* __restrict__ sb, bf16* __restrict__ wb) {
  const int i = blockIdx.x * blockDim.x + threadIdx.x;
  const int nAct4 = MTOT * DM / 4;
  const int nW4 = DM * DM / 4;
  const float* src;
  bf16* dst;
  int idx;
  if (i < nAct4) {
    src = s; dst = sb; idx = i;
  } else {
    const int j = i - nAct4;
    const int seg = j >> 20;                 // nW4 == 2^20
    src = (seg == 0) ? w0 : (seg == 1) ? w1 : (seg == 2) ? w2 : w3;
    dst = wb + ((size_t)seg << 20) * 4;
    idx = j & (nW4 - 1);
  }
  float4 v = reinterpret_cast<const float4*>(src)[idx];
  bf16x4v o;
  o[0] = (bf16)v.x; o[1] = (bf16)v.y; o[2] = (bf16)v.z; o[3] = (bf16)v.w;
  *reinterpret_cast<bf16x4v*>(dst + (size_t)idx * 4) = o;
}

// ---------------- fp32 -> fp16 cast (bias mask) ----------------
__global__ void cast_half_kernel(const float* __restrict__ in, f16* __restrict__ out, int n4) {
  int i = blockIdx.x * blockDim.x + threadIdx.x;
  if (i < n4) {
    float4 v = reinterpret_cast<const float4*>(in)[i];
    f16x4 o;
    o[0] = (f16)v.x; o[1] = (f16)v.y; o[2] = (f16)v.z; o[3] = (f16)v.w;
    *reinterpret_cast<f16x4*>(out + (size_t)i * 4) = o;
  }
}

// ---------------- merged QKV GEMM (128x128 tile, 4 waves — R7-proven structure) ----------------
// C[M, 6144] = A[M,K] * Wcat[6144,K]^T + bias(third).  col0>>11 selects q/k/v output.
__global__ __launch_bounds__(256, 2) void qkv_gemm(
    const bf16* __restrict__ A, const bf16* __restrict__ Wcat,
    const float* __restrict__ qb, const float* __restrict__ kb, const float* __restrict__ vb,
    bf16* __restrict__ qo, bf16* __restrict__ ko, bf16* __restrict__ vo) {
  __shared__ bf16 lA[128 * 64];
  __shared__ bf16 lB[128 * 64];

  const int tid = threadIdx.x;
  const int lane = tid & 63;
  const int wid = tid >> 6;
  const int wr = wid >> 1, wc = wid & 1;
  const int row0 = blockIdx.y * 128;
  const int col0 = blockIdx.x * 128;
  const int third = col0 >> 11;              // 0=q, 1=k, 2=v
  const float* bias = (third == 0) ? qb : (third == 1) ? kb : vb;

  const int srow = lane >> 3;
  const int scol = ((lane & 7) ^ srow) * 8;

  const int fr = lane & 15;
  const int fg = lane >> 4;

  f32x4 acc[4][4];
#pragma unroll
  for (int m = 0; m < 4; ++m)
#pragma unroll
    for (int n = 0; n < 4; ++n) { f32x4 z = {0.f, 0.f, 0.f, 0.f}; acc[m][n] = z; }

  for (int kt = 0; kt < DM / 64; ++kt) {
    const int k0 = kt * 64;
    __syncthreads();
#pragma unroll
    for (int i = 0; i < 4; ++i) {
      const int chunk = wid * 4 + i;
      const int r = chunk * 8 + srow;
      gload_lds16(A + (size_t)(row0 + r) * DM + k0 + scol, lA + chunk * 512);
      gload_lds16(Wcat + (size_t)(col0 + r) * DM + k0 + scol, lB + chunk * 512);
    }
    __syncthreads();
#pragma unroll
    for (int kk = 0; kk < 2; ++kk) {
      bf16x8 af[4], bw[4];
#pragma unroll
      for (int m = 0; m < 4; ++m) {
        const int r = wr * 64 + m * 16 + fr;
        const int cb = (kk * 64 + fg * 16) ^ ((r & 7) << 4);
        af[m] = *(const bf16x8*)((const char*)lA + r * 128 + cb);
      }
#pragma unroll
      for (int n = 0; n < 4; ++n) {
        const int r = wc * 64 + n * 16 + fr;
        const int cb = (kk * 64 + fg * 16) ^ ((r & 7) << 4);
        bw[n] = *(const bf16x8*)((const char*)lB + r * 128 + cb);
      }
#pragma unroll
      for (int m = 0; m < 4; ++m)
#pragma unroll
        for (int n = 0; n < 4; ++n) acc[m][n] = mfma16(af[m], bw[n], acc[m][n]);
    }
  }

#pragma unroll
  for (int m = 0; m < 4; ++m) {
#pragma unroll
    for (int n = 0; n < 4; ++n) {
      const int colg = col0 + wc * 64 + n * 16 + fr;
      const int col = colg & 2047;           // within third
      const float bs = bias[col];
      const int rbase = row0 + wr * 64 + m * 16 + fg * 4;
      const int h = col >> 7, d = col & 127;
      if (third < 2) {
        bf16* o = (third == 0) ? qo : ko;
#pragma unroll
        for (int r = 0; r < 4; ++r) {
          const int row = rbase + r;
          const int b = row >> 11, s = row & 2047;
          o[(((size_t)(b * NH + h) * SEQ + s) << 7) + d] = (bf16)(acc[m][n][r] + bs);
        }
      } else {
        const int b = rbase >> 11, s = rbase & 2047;
        bf16x4v pk;
#pragma unroll
        for (int r = 0; r < 4; ++r) pk[r] = (bf16)(acc[m][n][r] + bs);
        *reinterpret_cast<bf16x4v*>(vo + ((size_t)((b * NH + h) * DK + d) * SEQ + s)) = pk;
      }
    }
  }
}

// ---------------- O-projection GEMM (128x128, f32 out — R7-proven) ----------------
__global__ __launch_bounds__(256, 2) void gemm_oproj(
    const bf16* __restrict__ A, const bf16* __restrict__ W,
    const float* __restrict__ bias, float* __restrict__ out) {
  __shared__ bf16 lA[128 * 64];
  __shared__ bf16 lB[128 * 64];

  const int tid = threadIdx.x;
  const int lane = tid & 63;
  const int wid = tid >> 6;
  const int wr = wid >> 1, wc = wid & 1;
  const int row0 = blockIdx.y * 128;
  const int col0 = blockIdx.x * 128;

  const int srow = lane >> 3;
  const int scol = ((lane & 7) ^ srow) * 8;

  const int fr = lane & 15;
  const int fg = lane >> 4;

  f32x4 acc[4][4];
#pragma unroll
  for (int m = 0; m < 4; ++m)
#pragma unroll
    for (int n = 0; n < 4; ++n) { f32x4 z = {0.f, 0.f, 0.f, 0.f}; acc[m][n] = z; }

  for (int kt = 0; kt < DM / 64; ++kt) {
    const int k0 = kt * 64;
    __syncthreads();
#pragma unroll
    for (int i = 0; i < 4; ++i) {
      const int chunk = wid * 4 + i;
      const int r = chunk * 8 + srow;
      gload_lds16(A + (size_t)(row0 + r) * DM + k0 + scol, lA + chunk * 512);
      gload_lds16(W + (size_t)(col0 + r) * DM + k0 + scol, lB + chunk * 512);
    }
    __syncthreads();
#pragma unroll
    for (int kk = 0; kk < 2; ++kk) {
      bf16x8 af[4], bw[4];
#pragma unroll
      for (int m = 0; m < 4; ++m) {
        const int r = wr * 64 + m * 16 + fr;
        const int cb = (kk * 64 + fg * 16) ^ ((r & 7) << 4);
        af[m] = *(const bf16x8*)((const char*)lA + r * 128 + cb);
      }
#pragma unroll
      for (int n = 0; n < 4; ++n) {
        const int r = wc * 64 + n * 16 + fr;
        const int cb = (kk * 64 + fg * 16) ^ ((r & 7) << 4);
        bw[n] = *(const bf16x8*)((const char*)lB + r * 128 + cb);
      }
#pragma unroll
      for (int m = 0; m < 4; ++m)
#pragma unroll
        for (int n = 0; n < 4; ++n) acc[m][n] = mfma16(af[m], bw[n], acc[m][n]);
    }
  }

#pragma unroll
  for (int m = 0; m < 4; ++m) {
#pragma unroll
    for (int n = 0; n < 4; ++n) {
      const int col = col0 + wc * 64 + n * 16 + fr;
      const float bs = bias[col];
      const int rbase = row0 + wr * 64 + m * 16 + fg * 4;
#pragma unroll
      for (int r = 0; r < 4; ++r) {
        const int row = rbase + r;
        out[(size_t)row * DM + col] = acc[m][n][r] + bs;
      }
    }
  }
}

// ---------------- flash attention: swapped QK^T, in-register softmax (R7, verified) ----------------
__global__ __launch_bounds__(256, 2) void attn_kernel(
    const bf16* __restrict__ Q,   // [B,H,S,DK]
    const bf16* __restrict__ K,   // [B,H,S,DK]
    const bf16* __restrict__ Vt,  // [B,H,DK,S]
    const f16* __restrict__ maskh,    // [B,S,S] fp16
    const float* __restrict__ hscale, // [NH]
    bf16* __restrict__ O) {           // [B,S,H,DK]
  __shared__ bf16 Kl[2][64 * 128];  // 256B rows, granule slot = col16 ^ (row&15)
  __shared__ bf16 Vl[2][64 * 128];  // pair-rows (vp=d>>1) of 256B, slot = gl ^ (vp&15)

  const int tid = threadIdx.x;
  const int lane = tid & 63;
  const int wv = tid >> 6;
  const int l31 = lane & 31;
  const int hi = lane >> 5;
  const int ksw16 = (l31 & 15) << 4;
  const int vpbase = l31 >> 1;
  const int pvg = (l31 & 1) * 8 + hi;

  const int bid = blockIdx.x;
  const int xcd = bid & 7;
  const int slot_ = bid >> 3;
  const int g = xcd + ((slot_ >> 4) << 3);
  const int h = slot_ & 15;
  const int qt = g & 15;
  const int b = g >> 4;
  const int q0 = qt * 128;

  const float ksc2 = 0.08838834764831845f * 1.44269504f;
  const float hs2 = hscale[h] * 1.44269504f;

  const size_t bh = (size_t)(b * NH + h);
  const bf16* Qb = Q + bh * SEQ * DK;
  const bf16* Kb = K + bh * SEQ * DK;
  const bf16* Vb = Vt + bh * (size_t)DK * SEQ;
  const f16*  Mrow = maskh + (size_t)b * SEQ * SEQ + (size_t)(q0 + wv * 32 + l31) * SEQ;

  bf16x8 qreg[8];
  {
    const bf16* qrow = Qb + (size_t)(q0 + wv * 32 + l31) * DK + hi * 8;
#pragma unroll
    for (int s = 0; s < 8; ++s) qreg[s] = *(const bf16x8*)(qrow + s * 16);
  }

  f32x16 acco[4];
#pragma unroll
  for (int nd = 0; nd < 4; ++nd) acco[nd] = (f32x16)(0.0f);
  float m_ = -3.0e38f, l_ = 0.f;

  const int st_sub = lane >> 4;
  const int st_gl0 = lane & 15;

#pragma unroll
  for (int i = 0; i < 4; ++i) {
    const int chunk = wv * 4 + i;
    {
      const int r = chunk * 4 + st_sub;
      const int gl = st_gl0 ^ (r & 15);
      gload_lds16(Kb + (size_t)r * DK + gl * 8, Kl[0] + chunk * 512);
    }
    {
      const int vp = chunk * 4 + st_sub;
      const int gl = st_gl0 ^ (vp & 15);
      const int d = 2 * vp + (gl >> 3);
      gload_lds16(Vb + (size_t)d * SEQ + (gl & 7) * 8, Vl[0] + chunk * 512);
    }
  }
  __syncthreads();

  for (int t = 0; t < NT; ++t) {
    const int kb0 = t * 64;
    const int cur = t & 1, nxt = cur ^ 1;
    const bf16* Kc = Kl[cur];
    const bf16* Vc = Vl[cur];

    f16x4 mk[2][4];
#pragma unroll
    for (int st = 0; st < 2; ++st)
#pragma unroll
      for (int c = 0; c < 4; ++c)
        mk[st][c] = *(const f16x4*)(Mrow + kb0 + st * 32 + c * 8 + hi * 4);

    if (t + 1 < NT) {
#pragma unroll
      for (int i = 0; i < 4; ++i) {
        const int chunk = wv * 4 + i;
        {
          const int r = chunk * 4 + st_sub;
          const int gl = st_gl0 ^ (r & 15);
          gload_lds16(Kb + (size_t)(kb0 + 64 + r) * DK + gl * 8, Kl[nxt] + chunk * 512);
        }
        {
          const int vp = chunk * 4 + st_sub;
          const int gl = st_gl0 ^ (vp & 15);
          const int d = 2 * vp + (gl >> 3);
          gload_lds16(Vb + (size_t)d * SEQ + kb0 + 64 + (gl & 7) * 8, Vl[nxt] + chunk * 512);
        }
      }
    }

    f32x16 p[2];
#pragma unroll
    for (int st = 0; st < 2; ++st) p[st] = (f32x16)(0.0f);
    __builtin_amdgcn_s_setprio(1);
#pragma unroll
    for (int s = 0; s < 8; ++s) {
      const int byteoff = (s * 32 + hi * 16) ^ ksw16;
      bf16x8 k0 = *(const bf16x8*)((const char*)Kc + (size_t)l31 * 256 + byteoff);
      bf16x8 k1 = *(const bf16x8*)((const char*)Kc + (size_t)(32 + l31) * 256 + byteoff);
      p[0] = mfma32(k0, qreg[s], p[0]);
      p[1] = mfma32(k1, qreg[s], p[1]);
    }
    __builtin_amdgcn_s_setprio(0);

    float lg[32];
#pragma unroll
    for (int st = 0; st < 2; ++st)
#pragma unroll
      for (int r = 0; r < 16; ++r)
        lg[st * 16 + r] = p[st][r] * ksc2 + (float)mk[st][r >> 2][r & 3] * hs2;

    float tm[16];
#pragma unroll
    for (int i = 0; i < 16; ++i) tm[i] = fmaxf(lg[i], lg[i + 16]);
#pragma unroll
    for (int i = 0; i < 8; ++i) tm[i] = fmaxf(tm[i], tm[i + 8]);
#pragma unroll
    for (int i = 0; i < 4; ++i) tm[i] = fmaxf(tm[i], tm[i + 4]);
    float mx = fmaxf(fmaxf(tm[0], tm[1]), fmaxf(tm[2], tm[3]));
    mx = fmaxf(mx, __shfl_xor(mx, 32));

    if (__any(mx - m_ > 11.5416f)) {
      const float mnew = fmaxf(m_, mx);
      const float sc = exp2_fast(m_ - mnew);
      m_ = mnew;
      l_ *= sc;
#pragma unroll
      for (int r = 0; r < 16; ++r) {
        const float scr = __shfl(sc, (r & 3) + 8 * (r >> 2) + 4 * hi);
#pragma unroll
        for (int nd = 0; nd < 4; ++nd) acco[nd][r] *= scr;
      }
    }

#pragma unroll
    for (int i = 0; i < 32; ++i) lg[i] = exp2_fast(lg[i] - m_);
    float ts[16];
#pragma unroll
    for (int i = 0; i < 16; ++i) ts[i] = lg[i] + lg[i + 16];
#pragma unroll
    for (int i = 0; i < 8; ++i) ts[i] = ts[i] + ts[i + 8];
#pragma unroll
    for (int i = 0; i < 4; ++i) ts[i] = ts[i] + ts[i + 4];
    float es = (ts[0] + ts[1]) + (ts[2] + ts[3]);
    es += __shfl_xor(es, 32);
    l_ += es;

    bf16x8 pa[4];
#pragma unroll
    for (int ks = 0; ks < 4; ++ks) {
      const int bo = (ks & 1) * 8 + ((ks >> 1) << 4);
      const uint32_t w0 = cvtpk(lg[bo + 0], lg[bo + 1]);
      const uint32_t w1 = cvtpk(lg[bo + 2], lg[bo + 3]);
      const uint32_t w2 = cvtpk(lg[bo + 4], lg[bo + 5]);
      const uint32_t w3 = cvtpk(lg[bo + 6], lg[bo + 7]);
      const uint32_t x0 = __shfl_xor(w0, 32);
      const uint32_t x1 = __shfl_xor(w1, 32);
      const uint32_t x2 = __shfl_xor(w2, 32);
      const uint32_t x3 = __shfl_xor(w3, 32);
      union { uint32_t u[4]; bf16x8 v; } pk;
      pk.u[0] = hi ? x2 : w0;
      pk.u[1] = hi ? x3 : w1;
      pk.u[2] = hi ? w2 : x0;
      pk.u[3] = hi ? w3 : x1;
      pa[ks] = pk.v;
    }

    __builtin_amdgcn_s_setprio(1);
#pragma unroll
    for (int nd = 0; nd < 4; ++nd) {
      const int vrow = (nd * 16 + vpbase) * 256;
#pragma unroll
      for (int ks = 0; ks < 4; ++ks) {
        const int slot = (pvg + ks * 2) ^ vpbase;
        bf16x8 vf = *(const bf16x8*)((const char*)Vc + vrow + slot * 16);
        acco[nd] = mfma32(pa[ks], vf, acco[nd]);
      }
    }
    __builtin_amdgcn_s_setprio(0);

    asm volatile("s_waitcnt vmcnt(0) lgkmcnt(0)" ::: "memory");
    __builtin_amdgcn_sched_barrier(0);
    __builtin_amdgcn_s_barrier();
  }

  const float inv = 1.f / l_;
#pragma unroll
  for (int r = 0; r < 16; ++r) {
    const int qloc = (r & 3) + 8 * (r >> 2) + 4 * hi;
    const float ivr = __shfl(inv, qloc);
    const int q_abs = q0 + wv * 32 + qloc;
    bf16* orow = O + (((size_t)(b * SEQ + q_abs) * NH + h) << 7) + l31;
#pragma unroll
    for (int nd = 0; nd < 4; ++nd) orow[nd * 32] = (bf16)(acco[nd][r] * ivr);
  }
}

extern "C" void kernel_launch(void* const* d_in, const int* in_sizes, int n_in,
                              void* d_out, int out_size, void* d_ws, size_t ws_size,
                              hipStream_t stream) {
  const float* states = (const float*)d_in[0];
  const float* maskp  = (const float*)d_in[1];
  const float* hscale = (const float*)d_in[2];
  const float* qw = (const float*)d_in[3];
  const float* qb = (const float*)d_in[4];
  const float* kw = (const float*)d_in[5];
  const float* kb = (const float*)d_in[6];
  const float* vw = (const float*)d_in[7];
  const float* vb = (const float*)d_in[8];
  const float* ow = (const float*)d_in[9];
  const float* ob = (const float*)d_in[10];

  char* ws = (char*)d_ws;
  const size_t SZ_ACT = (size_t)MTOT * DM * 2;  // 16 MiB
  const size_t SZ_W   = (size_t)DM * DM * 2;    // 8 MiB
  bf16* sb    = (bf16*)(ws);                    // states bf16; later reused as O buffer
  bf16* qbuf  = (bf16*)(ws + SZ_ACT);
  bf16* kbuf  = (bf16*)(ws + 2 * SZ_ACT);
  bf16* vtbuf = (bf16*)(ws + 3 * SZ_ACT);
  bf16* wcat  = (bf16*)(ws + 4 * SZ_ACT);       // wq|wk|wv|wo contiguous (4 x SZ_W)
  bf16* wob   = (bf16*)(ws + 4 * SZ_ACT + 3 * SZ_W);
  f16* maskh  = (f16*)(ws + 4 * SZ_ACT);        // aliases wq|wk region (dead after QKV GEMM)

  const int nAct4 = MTOT * DM / 4;
  const int nW4   = DM * DM / 4;
  const int nM4   = NB * SEQ * SEQ / 4;

  // fused cast: states + qw|kw|vw|ow -> sb + wcat (one launch)
  cast_all_kernel<<<(nAct4 + 4 * nW4) / 256, 256, 0, stream>>>(states, qw, kw, vw, ow, sb, wcat);

  // merged QKV GEMM: N = 6144 over contiguous Wcat
  qkv_gemm<<<dim3(3 * DM / 128, MTOT / 128), dim3(256), 0, stream>>>(
      sb, wcat, qb, kb, vb, qbuf, kbuf, vtbuf);

  // mask cast AFTER QKV GEMM (overwrites wq|wk region)
  cast_half_kernel<<<(nM4 + 255) / 256, 256, 0, stream>>>(maskp, maskh, nM4);

  attn_kernel<<<dim3(NB * NH * (SEQ / 128)), dim3(256), 0, stream>>>(
      qbuf, kbuf, vtbuf, maskh, hscale, sb);

  gemm_oproj<<<dim3(DM / 128, MTOT / 128), dim3(256), 0, stream>>>(sb, wob, ob, (float*)d_out);
}